// Round 8
// baseline (2427.159 us; speedup 1.0000x reference)
//
#include <hip/hip_runtime.h>

#define P_   24
#define H_   24
#define E_   300
#define D_   512
#define TWOD 1024
#define G4   4096
#define SMEMB  27648
#define SMEMG  36864

typedef __attribute__((ext_vector_type(8))) short bf16x8;
typedef __attribute__((ext_vector_type(4))) float f32x4;

__device__ __forceinline__ float bf2f(unsigned int u) {
    return __uint_as_float(u << 16);
}
__device__ __forceinline__ unsigned short f2bf(float f) {
    unsigned int x = __float_as_uint(f);
    unsigned int r = (x + 0x7fffu + ((x >> 16) & 1u)) >> 16;
    return (unsigned short)r;
}
__device__ __forceinline__ float sigf(float x) {
    return 1.0f / (1.0f + __expf(-x));
}
__device__ __forceinline__ float tanh_f(float x) {
    return 2.0f / (1.0f + __expf(-2.0f * x)) - 1.0f;
}

// ---------------- workspace byte offsets ----------------
#define OFF_WHHP 0u           // packed Whh bf16: [nt=32][q=4][u=32][k=1024]
#define OFF_WCHB 8388608u     // 512*1024 bf16
#define OFF_WCCB 9437184u     // 512*1024 bf16
#define OFF_APRE 10485760u    // 768*4096 bf16
#define OFF_CPRE 16777216u    // 768*4096 bf16
#define OFF_PX   23068672u    // 768*320 bf16
#define OFF_HX   23560192u    // 768*320 bf16
#define OFF_HBB  24051712u    // 2*24*32*512 bf16 (h state, parity buffers)
#define OFF_CBF  25624576u    // 2*24*32*512 f32  (c state)
#define OFF_H2B  28770304u    // 24*32*1024 bf16
#define OFF_C2B  30343168u    // 24*32*1024 bf16
#define OFF_HF   31916032u    // 24*32*512 f32 (final h for MLP)
#define OFF_T1   33488896u    // 32*512 f32
#define OFF_T2   33554432u    // 32*512 f32

// ============ P0: weight convert/pack + embedding gather (grid 512) ========
__global__ __launch_bounds__(256) void k_p0(
        const int* __restrict__ prem, const int* __restrict__ hyp,
        const float* __restrict__ emb, const float* __restrict__ Whh,
        const float* __restrict__ Wch, const float* __restrict__ Wcc,
        char* __restrict__ wsb) {
    unsigned short* WhhP = (unsigned short*)(wsb + OFF_WHHP);
    unsigned short* WchB = (unsigned short*)(wsb + OFF_WCHB);
    unsigned short* WccB = (unsigned short*)(wsb + OFF_WCCB);
    unsigned short* PX   = (unsigned short*)(wsb + OFF_PX);
    unsigned short* HX   = (unsigned short*)(wsb + OFF_HX);

    int gt = blockIdx.x * 256 + threadIdx.x;
    int stride = gridDim.x * 256;
    // Whh: convert + permute rows n=q*1024+nt*32+u -> pr=nt*128+q*32+u
    for (int idx = gt; idx < 524288; idx += stride) {
        int n = idx >> 7;              // original row
        int k8 = (idx & 127) * 8;      // col start
        int q = n >> 10, rest = n & 1023;
        int nt = rest >> 5, u = rest & 31;
        int pr = nt * 128 + q * 32 + u;
        const float* s = Whh + (size_t)n * TWOD + k8;
        float4 va = *(const float4*)s, vb = *(const float4*)(s + 4);
        unsigned short o[8] = {f2bf(va.x), f2bf(va.y), f2bf(va.z), f2bf(va.w),
                               f2bf(vb.x), f2bf(vb.y), f2bf(vb.z), f2bf(vb.w)};
        *(uint4*)(WhhP + (size_t)pr * TWOD + k8) = *(const uint4*)o;
    }
    for (int idx = gt; idx < 131072; idx += stride) {
        int cc = idx & 65535;
        const float* s = ((idx < 65536) ? Wch : Wcc) + (size_t)cc * 8;
        unsigned short* dp = ((idx < 65536) ? WchB : WccB) + (size_t)cc * 8;
        float4 va = *(const float4*)s, vb = *(const float4*)(s + 4);
        unsigned short o[8] = {f2bf(va.x), f2bf(va.y), f2bf(va.z), f2bf(va.w),
                               f2bf(vb.x), f2bf(vb.y), f2bf(vb.z), f2bf(vb.w)};
        *(uint4*)dp = *(const uint4*)o;
    }
    for (int idx = gt; idx < 61440; idx += stride) {
        int isH = idx >= 30720 ? 1 : 0;
        int id2 = idx - isH * 30720;
        int rb = id2 / 40, c8 = (id2 % 40) * 8;
        int ri = rb >> 5, rbb = rb & 31;
        int tok = isH ? hyp[rbb * H_ + ri] : prem[rbb * P_ + ri];
        const float* s = emb + (size_t)tok * E_ + c8;
        unsigned short o[8];
        for (int e = 0; e < 8; ++e)
            o[e] = (c8 + e < E_) ? f2bf(s[e]) : (unsigned short)0;
        *(uint4*)((isH ? HX : PX) + rb * 320 + c8) = *(const uint4*)o;
    }
}

// ============ P1: Apre/Cpre GEMM, 64x128 tiles, K=320 (grid 768) ===========
__global__ __launch_bounds__(256) void k_p1(
        const float* __restrict__ Wih, const float* __restrict__ bih,
        const float* __restrict__ bhh, char* __restrict__ wsb) {
    const unsigned short* PX = (const unsigned short*)(wsb + OFF_PX);
    const unsigned short* HX = (const unsigned short*)(wsb + OFF_HX);
    unsigned short* Apre = (unsigned short*)(wsb + OFF_APRE);
    unsigned short* Cpre = (unsigned short*)(wsb + OFF_CPRE);

    __shared__ __align__(16) unsigned char smem[SMEMB];
    const int t = threadIdx.x;
    const int lane = t & 63, wvi = t >> 6, l16 = lane & 15, quad = lane >> 4;
    const int wm = wvi >> 1, wn = wvi & 1;
    unsigned short (*At)[72] = (unsigned short (*)[72])smem;            // 64 rows
    unsigned short (*Bt)[72] = (unsigned short (*)[72])(smem + 9216);   // 128 rows

    int q = blockIdx.x;
    int x = q & 7, slot = q >> 3;
    int z = slot / 48, rem = slot % 48;
    int ntg = rem / 12, mt = rem % 12;
    int nt = ntg * 8 + x;
    const unsigned short* X = z ? HX : PX;
    int koff = z ? E_ : 0;
    unsigned short* Out = z ? Cpre : Apre;
    f32x4 acc[2][4] = {};
    int arow = t >> 2, acol = (t & 3) * 16;
    int brow = t >> 1, bcol = (t & 1) * 32;
    for (int s = 0; s < 5; ++s) {
        int k0 = s * 64;
        {
            const uint4* src = (const uint4*)(X + (size_t)(mt * 64 + arow) * 320 + k0 + acol);
            uint4* dst = (uint4*)&At[arow][acol];
            dst[0] = src[0]; dst[1] = src[1];
        }
        {
            int n = nt * 128 + brow;
            const float* wrow = Wih + (size_t)n * (2 * E_) + koff;
            unsigned short* dst = &Bt[brow][bcol];
            for (int c4 = 0; c4 < 8; ++c4) {
                int k = k0 + bcol + c4 * 4;
                if (k < E_) {
                    float4 v = *(const float4*)(wrow + k);
                    dst[c4 * 4 + 0] = f2bf(v.x); dst[c4 * 4 + 1] = f2bf(v.y);
                    dst[c4 * 4 + 2] = f2bf(v.z); dst[c4 * 4 + 3] = f2bf(v.w);
                } else {
                    dst[c4 * 4 + 0] = 0; dst[c4 * 4 + 1] = 0;
                    dst[c4 * 4 + 2] = 0; dst[c4 * 4 + 3] = 0;
                }
            }
        }
        __syncthreads();
        for (int ks = 0; ks < 2; ++ks) {
            bf16x8 a[2], bb[4];
            for (int mi = 0; mi < 2; ++mi)
                a[mi] = *(const bf16x8*)&At[wm * 32 + mi * 16 + l16][ks * 32 + quad * 8];
            for (int ni = 0; ni < 4; ++ni)
                bb[ni] = *(const bf16x8*)&Bt[wn * 64 + ni * 16 + l16][ks * 32 + quad * 8];
            for (int mi = 0; mi < 2; ++mi)
                for (int ni = 0; ni < 4; ++ni)
                    acc[mi][ni] = __builtin_amdgcn_mfma_f32_16x16x32_bf16(
                        a[mi], bb[ni], acc[mi][ni], 0, 0, 0);
        }
        __syncthreads();
    }
    for (int mi = 0; mi < 2; ++mi) {
        int rbase = mt * 64 + wm * 32 + mi * 16 + quad * 4;
        for (int ni = 0; ni < 4; ++ni) {
            int n = nt * 128 + wn * 64 + ni * 16 + l16;
            float bias = z ? 0.0f : (bih[n] + bhh[n]);
            for (int r = 0; r < 4; ++r)
                Out[(size_t)(rbase + r) * G4 + n] = f2bf(acc[mi][ni][r] + bias);
        }
    }
}

// ====== gates: job=(cell-pair,nt), 64x128 tile, K=1024 (grid npairs*32) ====
// nt = ntg*8 + (bid%8) -> XCD-pinned N-slices. Two diagonal cells per block.
__global__ __launch_bounds__(256) void k_gates(int d, int npairs, char* __restrict__ wsb) {
    const unsigned short* WhhP = (const unsigned short*)(wsb + OFF_WHHP);
    const unsigned short* Apre = (const unsigned short*)(wsb + OFF_APRE);
    const unsigned short* Cpre = (const unsigned short*)(wsb + OFF_CPRE);
    const unsigned short* HbB  = (const unsigned short*)(wsb + OFF_HBB);
    const float*          Cbf  = (const float*)(wsb + OFF_CBF);
    unsigned short* H2B = (unsigned short*)(wsb + OFF_H2B);
    unsigned short* C2B = (unsigned short*)(wsb + OFF_C2B);

    int j_lo = (d > P_ - 1) ? d - (P_ - 1) : 0;
    int j_hi = (d < H_ - 1) ? d : H_ - 1;
    int ncells = j_hi - j_lo + 1;

    int x = blockIdx.x & 7, slot = blockIdx.x >> 3;
    int ntg = slot / npairs, pair = slot - ntg * npairs;
    int nt = ntg * 8 + x;
    int c0 = pair * 2;

    const unsigned short* HpB = HbB + (size_t)((d + 1) & 1) * (H_ * 32 * D_);
    const float* Cp = Cbf + (size_t)((d + 1) & 1) * (H_ * 32 * D_);

    __shared__ __align__(16) unsigned char smem[SMEMG];
    unsigned short (*At)[72] = (unsigned short (*)[72])smem;            // 64 rows
    unsigned short (*Bt)[72] = (unsigned short (*)[72])(smem + 9216);   // 128 rows
    float* Dt = (float*)smem;                                           // [64][132]

    const int t = threadIdx.x;
    const int lane = t & 63, wvi = t >> 6, l16 = lane & 15, quad = lane >> 4;
    const int wm = wvi >> 1, wn = wvi & 1;

    f32x4 acc[2][4] = {};
    int arow = t >> 2, acol = (t & 3) * 16;       // 64 rows x 64 cols / step
    int brow = t >> 1, bcol = (t & 1) * 32;       // 128 rows x 64 cols / step
    int ca = c0 + (arow >> 5), ra = arow & 31;
    bool avalid = (ca < ncells);
    int cja = j_lo + ca, cia = d - cja;
    const unsigned short* asrcL =
        (avalid && cia > 0) ? HpB + (size_t)(cja * 32 + ra) * D_ : nullptr;
    const unsigned short* asrcD =
        (avalid && cja > 0) ? HpB + (size_t)((cja - 1) * 32 + ra) * D_ : nullptr;
    const unsigned short* wsrc = WhhP + (size_t)(nt * 128 + brow) * TWOD + bcol;

    for (int s = 0; s < 16; ++s) {
        int k0 = s * 64;
        {   // A: 16-col chunks never straddle the 512 boundary (16 | 512)
            for (int h8 = 0; h8 < 2; ++h8) {
                int kk = k0 + acol + h8 * 8;
                const unsigned short* sp =
                    (kk < D_) ? (asrcL ? asrcL + kk : nullptr)
                              : (asrcD ? asrcD + (kk - D_) : nullptr);
                uint4 v;
                if (sp) v = *(const uint4*)sp;
                else { v.x = 0u; v.y = 0u; v.z = 0u; v.w = 0u; }
                *(uint4*)&At[arow][acol + h8 * 8] = v;
            }
        }
        {   // B: packed contiguous rows
            const uint4* s4 = (const uint4*)(wsrc + k0);
            uint4* dp = (uint4*)&Bt[brow][bcol];
            dp[0] = s4[0]; dp[1] = s4[1]; dp[2] = s4[2]; dp[3] = s4[3];
        }
        __syncthreads();
        for (int ks = 0; ks < 2; ++ks) {
            bf16x8 a[2], bb[4];
            for (int mi = 0; mi < 2; ++mi)
                a[mi] = *(const bf16x8*)&At[wm * 32 + mi * 16 + l16][ks * 32 + quad * 8];
            for (int ni = 0; ni < 4; ++ni)
                bb[ni] = *(const bf16x8*)&Bt[wn * 64 + ni * 16 + l16][ks * 32 + quad * 8];
            for (int mi = 0; mi < 2; ++mi)
                for (int ni = 0; ni < 4; ++ni)
                    acc[mi][ni] = __builtin_amdgcn_mfma_f32_16x16x32_bf16(
                        a[mi], bb[ni], acc[mi][ni], 0, 0, 0);
        }
        __syncthreads();
    }
    // epilogue: acc -> LDS (f32 D tile) -> fused LSTM activation
    for (int mi = 0; mi < 2; ++mi) {
        int rr = wm * 32 + mi * 16 + quad * 4;
        for (int ni = 0; ni < 4; ++ni) {
            int cc2 = wn * 64 + ni * 16 + l16;
            for (int r = 0; r < 4; ++r)
                Dt[(rr + r) * 132 + cc2] = acc[mi][ni][r];
        }
    }
    __syncthreads();
    {
        int u = t & 31, r0 = (t >> 5) * 8;
        int k = nt * 32 + u;
        for (int r = r0; r < r0 + 8; ++r) {
            int cell = c0 + (r >> 5);
            if (cell < ncells) {
                int rb = r & 31;
                int cj = j_lo + cell, ci = d - cj;
                size_t ai = (size_t)(ci * 32 + rb) * G4 + k;
                size_t cix = (size_t)(cj * 32 + rb) * G4 + k;
                float g0 = Dt[r * 132 +      u] + bf2f(Apre[ai])        + bf2f(Cpre[cix]);
                float g1 = Dt[r * 132 + 32 + u] + bf2f(Apre[ai + 1024]) + bf2f(Cpre[cix + 1024]);
                float g2 = Dt[r * 132 + 64 + u] + bf2f(Apre[ai + 2048]) + bf2f(Cpre[cix + 2048]);
                float g3 = Dt[r * 132 + 96 + u] + bf2f(Apre[ai + 3072]) + bf2f(Cpre[cix + 3072]);
                float ccat;
                if (k < D_) ccat = (ci > 0) ? Cp[(size_t)(cj * 32 + rb) * D_ + k] : 0.0f;
                else        ccat = (cj > 0) ? Cp[(size_t)((cj - 1) * 32 + rb) * D_ + (k - D_)] : 0.0f;
                float si = sigf(g0), sf = sigf(g1), tg = tanh_f(g2), so = sigf(g3);
                float c2v = sf * ccat + si * tg;
                float h2v = so * tanh_f(c2v);
                H2B[(size_t)(cell * 32 + rb) * TWOD + k] = f2bf(h2v);
                C2B[(size_t)(cell * 32 + rb) * TWOD + k] = f2bf(c2v);
            }
        }
    }
}

// ===== cond: job=(z,ntile,mt), 64x128 tile, K=1024 (grid ceil(nc/2)*8) =====
__global__ __launch_bounds__(256) void k_cond(
        int d, const float* __restrict__ bch, const float* __restrict__ bcc,
        char* __restrict__ wsb) {
    const unsigned short* H2B  = (const unsigned short*)(wsb + OFF_H2B);
    const unsigned short* C2B  = (const unsigned short*)(wsb + OFF_C2B);
    const unsigned short* WchB = (const unsigned short*)(wsb + OFF_WCHB);
    const unsigned short* WccB = (const unsigned short*)(wsb + OFF_WCCB);
    unsigned short* HbB = (unsigned short*)(wsb + OFF_HBB);
    float* Cbf = (float*)(wsb + OFF_CBF);
    float* Hf  = (float*)(wsb + OFF_HF);

    int j_lo = (d > P_ - 1) ? d - (P_ - 1) : 0;
    int j_hi = (d < H_ - 1) ? d : H_ - 1;
    int Mrows = (j_hi - j_lo + 1) * 32;
    int xcd = blockIdx.x & 7, mt = blockIdx.x >> 3;
    if (mt * 64 >= Mrows) return;
    int z = xcd >> 2, ntile = xcd & 3;
    const unsigned short* Ain = z ? C2B : H2B;
    const unsigned short* W = z ? WccB : WchB;

    __shared__ __align__(16) unsigned char smem[SMEMB];
    unsigned short (*At)[72] = (unsigned short (*)[72])smem;            // 64 rows
    unsigned short (*Bt)[72] = (unsigned short (*)[72])(smem + 9216);   // 128 rows

    const int t = threadIdx.x;
    const int lane = t & 63, wvi = t >> 6, l16 = lane & 15, quad = lane >> 4;
    const int wm = wvi >> 1, wn = wvi & 1;
    unsigned short* HbC = HbB + (size_t)(d & 1) * (H_ * 32 * D_);
    float* CbC = Cbf + (size_t)(d & 1) * (H_ * 32 * D_);

    f32x4 acc[2][4] = {};
    int arow = t >> 2, acol = (t & 3) * 16;
    int rm0 = mt * 64 + arow;
    int brow = t >> 1, bcol = (t & 1) * 32;
    const unsigned short* wsrc = W + (size_t)(ntile * 128 + brow) * TWOD + bcol;
    const unsigned short* asrc =
        (rm0 < Mrows) ? Ain + (size_t)rm0 * TWOD + acol : nullptr;
    for (int s = 0; s < 16; ++s) {
        int k0 = s * 64;
        {
            uint4 v0, v1;
            if (asrc) {
                v0 = *(const uint4*)(asrc + k0);
                v1 = *(const uint4*)(asrc + k0 + 8);
            } else {
                v0.x = v0.y = v0.z = v0.w = 0u;
                v1 = v0;
            }
            *(uint4*)&At[arow][acol] = v0;
            *(uint4*)&At[arow][acol + 8] = v1;
        }
        {
            const uint4* s4 = (const uint4*)(wsrc + k0);
            uint4* dp = (uint4*)&Bt[brow][bcol];
            dp[0] = s4[0]; dp[1] = s4[1]; dp[2] = s4[2]; dp[3] = s4[3];
        }
        __syncthreads();
        for (int ks = 0; ks < 2; ++ks) {
            bf16x8 a[2], bb[4];
            for (int mi = 0; mi < 2; ++mi)
                a[mi] = *(const bf16x8*)&At[wm * 32 + mi * 16 + l16][ks * 32 + quad * 8];
            for (int ni = 0; ni < 4; ++ni)
                bb[ni] = *(const bf16x8*)&Bt[wn * 64 + ni * 16 + l16][ks * 32 + quad * 8];
            for (int mi = 0; mi < 2; ++mi)
                for (int ni = 0; ni < 4; ++ni)
                    acc[mi][ni] = __builtin_amdgcn_mfma_f32_16x16x32_bf16(
                        a[mi], bb[ni], acc[mi][ni], 0, 0, 0);
        }
        __syncthreads();
    }
    for (int mi = 0; mi < 2; ++mi) {
        int rbase = mt * 64 + wm * 32 + mi * 16 + quad * 4;
        for (int ni = 0; ni < 4; ++ni) {
            int n = ntile * 128 + wn * 64 + ni * 16 + l16;
            float bsv = z ? bcc[n] : bch[n];
            for (int r = 0; r < 4; ++r) {
                int rm = rbase + r;
                if (rm < Mrows) {
                    int cj = j_lo + (rm >> 5), rb = rm & 31;
                    float val = acc[mi][ni][r] + bsv;
                    if (z) {
                        CbC[(size_t)(cj * 32 + rb) * D_ + n] = val;
                    } else {
                        HbC[(size_t)(cj * 32 + rb) * D_ + n] = f2bf(val);
                        if (d == P_ + H_ - 2)
                            Hf[(size_t)(cj * 32 + rb) * D_ + n] = val;
                    }
                }
            }
        }
    }
}

// ============ MLP head =====================================================
__global__ __launch_bounds__(256) void k_fc(
        const float* __restrict__ hin, const float* __restrict__ W,
        const float* __restrict__ bias, float* __restrict__ outv) {
    int g = blockIdx.x * 256 + threadIdx.x;   // 16384 total
    int col = g & 511, rb = g >> 9;
    const float* h = hin + (size_t)rb * D_;
    const float* w = W + (size_t)col * D_;
    float accv = bias[col];
    for (int k = 0; k < D_; k += 4) {
        float4 wv4 = *(const float4*)(w + k);
        float4 hv = *(const float4*)(h + k);
        accv += hv.x * wv4.x + hv.y * wv4.y + hv.z * wv4.z + hv.w * wv4.w;
    }
    outv[(size_t)rb * D_ + col] = fmaxf(accv, 0.0f);
}

__global__ __launch_bounds__(128) void k_sm(
        const float* __restrict__ T2, const float* __restrict__ W3,
        const float* __restrict__ b3, float* __restrict__ out) {
    __shared__ float lg[96];
    int t = threadIdx.x;
    if (t < 96) {
        int rb = t / 3, cls = t % 3;
        const float* h = T2 + (size_t)rb * D_;
        const float* w = W3 + (size_t)cls * D_;
        float accv = b3[cls];
        for (int k = 0; k < D_; k += 4) {
            float4 wv4 = *(const float4*)(w + k);
            float4 hv = *(const float4*)(h + k);
            accv += hv.x * wv4.x + hv.y * wv4.y + hv.z * wv4.z + hv.w * wv4.w;
        }
        lg[rb * 3 + cls] = accv;
    }
    __syncthreads();
    if (t < 32) {
        float a = lg[t * 3 + 0], bq = lg[t * 3 + 1], cq = lg[t * 3 + 2];
        float m = fmaxf(a, fmaxf(bq, cq));
        float ea = __expf(a - m), eb = __expf(bq - m), ec = __expf(cq - m);
        float s = 1.0f / (ea + eb + ec);
        out[t * 3 + 0] = ea * s;
        out[t * 3 + 1] = eb * s;
        out[t * 3 + 2] = ec * s;
    }
}

// ---------------------------------------------------------------------------
extern "C" void kernel_launch(void* const* d_in, const int* in_sizes, int n_in,
                              void* d_out, int out_size, void* d_ws, size_t ws_size,
                              hipStream_t stream) {
    (void)in_sizes; (void)n_in; (void)out_size; (void)ws_size;

    const int* prem = (const int*)d_in[0];
    const int* hyp  = (const int*)d_in[1];
    const float* emb = (const float*)d_in[2];
    const float* Wih = (const float*)d_in[3];
    const float* Whh = (const float*)d_in[4];
    const float* bih = (const float*)d_in[5];
    const float* bhh = (const float*)d_in[6];
    const float* Wch = (const float*)d_in[7];
    const float* bch = (const float*)d_in[8];
    const float* Wcc = (const float*)d_in[9];
    const float* bcc = (const float*)d_in[10];
    const float* W1  = (const float*)d_in[11];
    const float* b1  = (const float*)d_in[12];
    const float* W2  = (const float*)d_in[13];
    const float* b2  = (const float*)d_in[14];
    const float* W3  = (const float*)d_in[15];
    const float* b3  = (const float*)d_in[16];
    float* outp = (float*)d_out;
    char* wsb = (char*)d_ws;

    float* Hf = (float*)(wsb + OFF_HF);
    float* T1 = (float*)(wsb + OFF_T1);
    float* T2 = (float*)(wsb + OFF_T2);

    k_p0<<<512, 256, 0, stream>>>(prem, hyp, emb, Whh, Wch, Wcc, wsb);
    k_p1<<<768, 256, 0, stream>>>(Wih, bih, bhh, wsb);
    for (int d = 0; d < P_ + H_ - 1; ++d) {
        int j_lo = (d > P_ - 1) ? d - (P_ - 1) : 0;
        int j_hi = (d < H_ - 1) ? d : H_ - 1;
        int ncells = j_hi - j_lo + 1;
        int npairs = (ncells + 1) >> 1;
        k_gates<<<npairs * 32, 256, 0, stream>>>(d, npairs, wsb);
        k_cond<<<npairs * 8, 256, 0, stream>>>(d, bch, bcc, wsb);
    }
    const float* hfin = Hf + (size_t)(H_ - 1) * 32 * D_;
    k_fc<<<64, 256, 0, stream>>>(hfin, W1, b1, T1);
    k_fc<<<64, 256, 0, stream>>>(T1, W2, b2, T2);
    k_sm<<<1, 128, 0, stream>>>(T2, W3, b3, outp);
}

// Round 9
// 1605.270 us; speedup vs baseline: 1.5120x; 1.5120x over previous
//
#include <hip/hip_runtime.h>

#define P_   24
#define H_   24
#define E_   300
#define D_   512
#define TWOD 1024
#define G4   4096
#define SMEMB  27648
#define BUFSZ  23040            // A(32x72x2=4608) + B(128x72x2=18432)
#define SMEMG2 46080            // two buffers

typedef __attribute__((ext_vector_type(8))) short bf16x8;
typedef __attribute__((ext_vector_type(4))) float f32x4;

__device__ __forceinline__ float bf2f(unsigned int u) {
    return __uint_as_float(u << 16);
}
__device__ __forceinline__ unsigned short f2bf(float f) {
    unsigned int x = __float_as_uint(f);
    unsigned int r = (x + 0x7fffu + ((x >> 16) & 1u)) >> 16;
    return (unsigned short)r;
}
__device__ __forceinline__ float sigf(float x) {
    return 1.0f / (1.0f + __expf(-x));
}
__device__ __forceinline__ float tanh_f(float x) {
    return 2.0f / (1.0f + __expf(-2.0f * x)) - 1.0f;
}

// ---------------- workspace byte offsets ----------------
#define OFF_WHHP 0u           // packed Whh bf16: [nt=32][q=4][u=32][k=1024]
#define OFF_WCHB 8388608u     // 512*1024 bf16
#define OFF_WCCB 9437184u     // 512*1024 bf16
#define OFF_APRE 10485760u    // 768*4096 bf16
#define OFF_CPRE 16777216u    // 768*4096 bf16
#define OFF_PX   23068672u    // 768*320 bf16
#define OFF_HX   23560192u    // 768*320 bf16
#define OFF_HBB  24051712u    // 2*24*32*512 bf16 (h state, parity buffers)
#define OFF_CBF  25624576u    // 2*24*32*512 f32  (c state)
#define OFF_H2B  28770304u    // 24*32*1024 bf16
#define OFF_C2B  30343168u    // 24*32*1024 bf16
#define OFF_HF   31916032u    // 24*32*512 f32 (final h for MLP)
#define OFF_T1   33488896u    // 32*512 f32
#define OFF_T2   33554432u    // 32*512 f32

// ============ P0: weight convert/pack + embedding gather (grid 512) ========
__global__ __launch_bounds__(256) void k_p0(
        const int* __restrict__ prem, const int* __restrict__ hyp,
        const float* __restrict__ emb, const float* __restrict__ Whh,
        const float* __restrict__ Wch, const float* __restrict__ Wcc,
        char* __restrict__ wsb) {
    unsigned short* WhhP = (unsigned short*)(wsb + OFF_WHHP);
    unsigned short* WchB = (unsigned short*)(wsb + OFF_WCHB);
    unsigned short* WccB = (unsigned short*)(wsb + OFF_WCCB);
    unsigned short* PX   = (unsigned short*)(wsb + OFF_PX);
    unsigned short* HX   = (unsigned short*)(wsb + OFF_HX);

    int gt = blockIdx.x * 256 + threadIdx.x;
    int stride = gridDim.x * 256;
    // Whh: convert + permute rows n=q*1024+nt*32+u -> pr=nt*128+q*32+u
    for (int idx = gt; idx < 524288; idx += stride) {
        int n = idx >> 7;              // original row
        int k8 = (idx & 127) * 8;      // col start
        int q = n >> 10, rest = n & 1023;
        int nt = rest >> 5, u = rest & 31;
        int pr = nt * 128 + q * 32 + u;
        const float* s = Whh + (size_t)n * TWOD + k8;
        float4 va = *(const float4*)s, vb = *(const float4*)(s + 4);
        unsigned short o[8] = {f2bf(va.x), f2bf(va.y), f2bf(va.z), f2bf(va.w),
                               f2bf(vb.x), f2bf(vb.y), f2bf(vb.z), f2bf(vb.w)};
        *(uint4*)(WhhP + (size_t)pr * TWOD + k8) = *(const uint4*)o;
    }
    for (int idx = gt; idx < 131072; idx += stride) {
        int cc = idx & 65535;
        const float* s = ((idx < 65536) ? Wch : Wcc) + (size_t)cc * 8;
        unsigned short* dp = ((idx < 65536) ? WchB : WccB) + (size_t)cc * 8;
        float4 va = *(const float4*)s, vb = *(const float4*)(s + 4);
        unsigned short o[8] = {f2bf(va.x), f2bf(va.y), f2bf(va.z), f2bf(va.w),
                               f2bf(vb.x), f2bf(vb.y), f2bf(vb.z), f2bf(vb.w)};
        *(uint4*)dp = *(const uint4*)o;
    }
    for (int idx = gt; idx < 61440; idx += stride) {
        int isH = idx >= 30720 ? 1 : 0;
        int id2 = idx - isH * 30720;
        int rb = id2 / 40, c8 = (id2 % 40) * 8;
        int ri = rb >> 5, rbb = rb & 31;
        int tok = isH ? hyp[rbb * H_ + ri] : prem[rbb * P_ + ri];
        const float* s = emb + (size_t)tok * E_ + c8;
        unsigned short o[8];
        for (int e = 0; e < 8; ++e)
            o[e] = (c8 + e < E_) ? f2bf(s[e]) : (unsigned short)0;
        *(uint4*)((isH ? HX : PX) + rb * 320 + c8) = *(const uint4*)o;
    }
}

// ============ P1: Apre/Cpre GEMM, 64x128 tiles, K=320 (grid 768) ===========
__global__ __launch_bounds__(256) void k_p1(
        const float* __restrict__ Wih, const float* __restrict__ bih,
        const float* __restrict__ bhh, char* __restrict__ wsb) {
    const unsigned short* PX = (const unsigned short*)(wsb + OFF_PX);
    const unsigned short* HX = (const unsigned short*)(wsb + OFF_HX);
    unsigned short* Apre = (unsigned short*)(wsb + OFF_APRE);
    unsigned short* Cpre = (unsigned short*)(wsb + OFF_CPRE);

    __shared__ __align__(16) unsigned char smem[SMEMB];
    const int t = threadIdx.x;
    const int lane = t & 63, wvi = t >> 6, l16 = lane & 15, quad = lane >> 4;
    const int wm = wvi >> 1, wn = wvi & 1;
    unsigned short (*At)[72] = (unsigned short (*)[72])smem;            // 64 rows
    unsigned short (*Bt)[72] = (unsigned short (*)[72])(smem + 9216);   // 128 rows

    int q = blockIdx.x;
    int x = q & 7, slot = q >> 3;
    int z = slot / 48, rem = slot % 48;
    int ntg = rem / 12, mt = rem % 12;
    int nt = ntg * 8 + x;
    const unsigned short* X = z ? HX : PX;
    int koff = z ? E_ : 0;
    unsigned short* Out = z ? Cpre : Apre;
    f32x4 acc[2][4] = {};
    int arow = t >> 2, acol = (t & 3) * 16;
    int brow = t >> 1, bcol = (t & 1) * 32;
    for (int s = 0; s < 5; ++s) {
        int k0 = s * 64;
        {
            const uint4* src = (const uint4*)(X + (size_t)(mt * 64 + arow) * 320 + k0 + acol);
            uint4* dst = (uint4*)&At[arow][acol];
            dst[0] = src[0]; dst[1] = src[1];
        }
        {
            int n = nt * 128 + brow;
            const float* wrow = Wih + (size_t)n * (2 * E_) + koff;
            unsigned short* dst = &Bt[brow][bcol];
            for (int c4 = 0; c4 < 8; ++c4) {
                int k = k0 + bcol + c4 * 4;
                if (k < E_) {
                    float4 v = *(const float4*)(wrow + k);
                    dst[c4 * 4 + 0] = f2bf(v.x); dst[c4 * 4 + 1] = f2bf(v.y);
                    dst[c4 * 4 + 2] = f2bf(v.z); dst[c4 * 4 + 3] = f2bf(v.w);
                } else {
                    dst[c4 * 4 + 0] = 0; dst[c4 * 4 + 1] = 0;
                    dst[c4 * 4 + 2] = 0; dst[c4 * 4 + 3] = 0;
                }
            }
        }
        __syncthreads();
        for (int ks = 0; ks < 2; ++ks) {
            bf16x8 a[2], bb[4];
            for (int mi = 0; mi < 2; ++mi)
                a[mi] = *(const bf16x8*)&At[wm * 32 + mi * 16 + l16][ks * 32 + quad * 8];
            for (int ni = 0; ni < 4; ++ni)
                bb[ni] = *(const bf16x8*)&Bt[wn * 64 + ni * 16 + l16][ks * 32 + quad * 8];
            for (int mi = 0; mi < 2; ++mi)
                for (int ni = 0; ni < 4; ++ni)
                    acc[mi][ni] = __builtin_amdgcn_mfma_f32_16x16x32_bf16(
                        a[mi], bb[ni], acc[mi][ni], 0, 0, 0);
        }
        __syncthreads();
    }
    for (int mi = 0; mi < 2; ++mi) {
        int rbase = mt * 64 + wm * 32 + mi * 16 + quad * 4;
        for (int ni = 0; ni < 4; ++ni) {
            int n = nt * 128 + wn * 64 + ni * 16 + l16;
            float bias = z ? 0.0f : (bih[n] + bhh[n]);
            for (int r = 0; r < 4; ++r)
                Out[(size_t)(rbase + r) * G4 + n] = f2bf(acc[mi][ni][r] + bias);
        }
    }
}

// ====== gates: job=(cell,nt), 32x128 tile, K=1024, double-buffered LDS =====
// grid = ncells*32 exact; nt = ntg*8 + (bid%8) -> XCD-pinned N-slices.
__global__ __launch_bounds__(256) void k_gates(int d, int ncells, char* __restrict__ wsb) {
    const unsigned short* WhhP = (const unsigned short*)(wsb + OFF_WHHP);
    const unsigned short* Apre = (const unsigned short*)(wsb + OFF_APRE);
    const unsigned short* Cpre = (const unsigned short*)(wsb + OFF_CPRE);
    const unsigned short* HbB  = (const unsigned short*)(wsb + OFF_HBB);
    const float*          Cbf  = (const float*)(wsb + OFF_CBF);
    unsigned short* H2B = (unsigned short*)(wsb + OFF_H2B);
    unsigned short* C2B = (unsigned short*)(wsb + OFF_C2B);

    int j_lo = (d > P_ - 1) ? d - (P_ - 1) : 0;

    int x = blockIdx.x & 7, slot = blockIdx.x >> 3;
    int ntg = slot / ncells, c = slot - ntg * ncells;
    int nt = ntg * 8 + x;
    int cj = j_lo + c, ci = d - cj;

    const unsigned short* HpB = HbB + (size_t)((d + 1) & 1) * (H_ * 32 * D_);
    const float* Cp = Cbf + (size_t)((d + 1) & 1) * (H_ * 32 * D_);

    __shared__ __align__(16) unsigned char smem[SMEMG2];
    const int t = threadIdx.x;
    const int lane = t & 63, wvi = t >> 6, l16 = lane & 15, quad = lane >> 4;

    f32x4 acc[2][2] = {};
    const int arow = t >> 3, acol = (t & 7) * 8;   // 16 B/thread A stage
    const int brow = t >> 1, bcol = (t & 1) * 32;  // 64 B/thread B stage
    const unsigned short* wsrc = WhhP + (size_t)(nt * 128 + brow) * TWOD + bcol;
    const unsigned short* asrcL =
        (ci > 0) ? HpB + (size_t)(cj * 32 + arow) * D_ : nullptr;
    const unsigned short* asrcD =
        (cj > 0) ? HpB + (size_t)((cj - 1) * 32 + arow) * D_ : nullptr;

    uint4 aR, bR0, bR1, bR2, bR3;
    #define LOAD_STEP(s_)                                                      \
        {                                                                      \
            int kk = (s_) * 64 + acol;                                         \
            const unsigned short* sp =                                         \
                (kk < D_) ? (asrcL ? asrcL + kk : nullptr)                     \
                          : (asrcD ? asrcD + (kk - D_) : nullptr);             \
            if (sp) aR = *(const uint4*)sp;                                    \
            else { aR.x = 0u; aR.y = 0u; aR.z = 0u; aR.w = 0u; }               \
            const uint4* s4 = (const uint4*)(wsrc + (s_) * 64);                \
            bR0 = s4[0]; bR1 = s4[1]; bR2 = s4[2]; bR3 = s4[3];                \
        }
    #define STORE_STEP(p_)                                                     \
        {                                                                      \
            unsigned short (*At_)[72] = (unsigned short (*)[72])(smem + (p_) * BUFSZ); \
            unsigned short (*Bt_)[72] = (unsigned short (*)[72])(smem + (p_) * BUFSZ + 4608); \
            *(uint4*)&At_[arow][acol] = aR;                                    \
            uint4* dp = (uint4*)&Bt_[brow][bcol];                              \
            dp[0] = bR0; dp[1] = bR1; dp[2] = bR2; dp[3] = bR3;                \
        }

    LOAD_STEP(0);
    STORE_STEP(0);
    __syncthreads();
    for (int s = 0; s < 16; ++s) {
        if (s < 15) LOAD_STEP(s + 1);
        int p = s & 1;
        unsigned short (*At)[72] = (unsigned short (*)[72])(smem + p * BUFSZ);
        unsigned short (*Bt)[72] = (unsigned short (*)[72])(smem + p * BUFSZ + 4608);
        for (int ks = 0; ks < 2; ++ks) {
            bf16x8 a0 = *(const bf16x8*)&At[l16][ks * 32 + quad * 8];
            bf16x8 a1 = *(const bf16x8*)&At[16 + l16][ks * 32 + quad * 8];
            bf16x8 b0 = *(const bf16x8*)&Bt[wvi * 32 + l16][ks * 32 + quad * 8];
            bf16x8 b1 = *(const bf16x8*)&Bt[wvi * 32 + 16 + l16][ks * 32 + quad * 8];
            acc[0][0] = __builtin_amdgcn_mfma_f32_16x16x32_bf16(a0, b0, acc[0][0], 0, 0, 0);
            acc[0][1] = __builtin_amdgcn_mfma_f32_16x16x32_bf16(a0, b1, acc[0][1], 0, 0, 0);
            acc[1][0] = __builtin_amdgcn_mfma_f32_16x16x32_bf16(a1, b0, acc[1][0], 0, 0, 0);
            acc[1][1] = __builtin_amdgcn_mfma_f32_16x16x32_bf16(a1, b1, acc[1][1], 0, 0, 0);
        }
        if (s < 15) {
            STORE_STEP(1 - p);
            __syncthreads();
        }
    }
    #undef LOAD_STEP
    #undef STORE_STEP

    // epilogue: acc -> LDS (aliases buf0; buf0 reads ended before s=15's sync,
    // buf1 region is disjoint) -> fused LSTM activation
    float* Dt = (float*)smem;   // [32][132]
    for (int mi = 0; mi < 2; ++mi)
        for (int ni = 0; ni < 2; ++ni) {
            int cc2 = wvi * 32 + ni * 16 + l16;
            int rr = mi * 16 + quad * 4;
            for (int r = 0; r < 4; ++r)
                Dt[(rr + r) * 132 + cc2] = acc[mi][ni][r];
        }
    __syncthreads();
    {
        int u = t & 31, r0 = (t >> 5) * 4;
        int k = nt * 32 + u;
        for (int r = r0; r < r0 + 4; ++r) {
            size_t ai = (size_t)(ci * 32 + r) * G4 + k;
            size_t cix = (size_t)(cj * 32 + r) * G4 + k;
            float g0 = Dt[r * 132 +      u] + bf2f(Apre[ai])        + bf2f(Cpre[cix]);
            float g1 = Dt[r * 132 + 32 + u] + bf2f(Apre[ai + 1024]) + bf2f(Cpre[cix + 1024]);
            float g2 = Dt[r * 132 + 64 + u] + bf2f(Apre[ai + 2048]) + bf2f(Cpre[cix + 2048]);
            float g3 = Dt[r * 132 + 96 + u] + bf2f(Apre[ai + 3072]) + bf2f(Cpre[cix + 3072]);
            float ccat;
            if (k < D_) ccat = (ci > 0) ? Cp[(size_t)(cj * 32 + r) * D_ + k] : 0.0f;
            else        ccat = (cj > 0) ? Cp[(size_t)((cj - 1) * 32 + r) * D_ + (k - D_)] : 0.0f;
            float si = sigf(g0), sf = sigf(g1), tg = tanh_f(g2), so = sigf(g3);
            float c2v = sf * ccat + si * tg;
            float h2v = so * tanh_f(c2v);
            H2B[(size_t)(c * 32 + r) * TWOD + k] = f2bf(h2v);
            C2B[(size_t)(c * 32 + r) * TWOD + k] = f2bf(c2v);
        }
    }
}

// ====== cond: job=(cell, z,ntile), 32x128 tile, K=1024, dbuf LDS ===========
// grid = ncells*8; (z,ntile) = bid%8 -> XCD-pinned weight slices.
__global__ __launch_bounds__(256) void k_cond(
        int d, const float* __restrict__ bch, const float* __restrict__ bcc,
        char* __restrict__ wsb) {
    const unsigned short* H2B  = (const unsigned short*)(wsb + OFF_H2B);
    const unsigned short* C2B  = (const unsigned short*)(wsb + OFF_C2B);
    const unsigned short* WchB = (const unsigned short*)(wsb + OFF_WCHB);
    const unsigned short* WccB = (const unsigned short*)(wsb + OFF_WCCB);
    unsigned short* HbB = (unsigned short*)(wsb + OFF_HBB);
    float* Cbf = (float*)(wsb + OFF_CBF);
    float* Hf  = (float*)(wsb + OFF_HF);

    int j_lo = (d > P_ - 1) ? d - (P_ - 1) : 0;
    int xcd = blockIdx.x & 7, c = blockIdx.x >> 3;
    int z = xcd >> 2, ntile = xcd & 3;
    const unsigned short* Ain = z ? C2B : H2B;
    const unsigned short* W = z ? WccB : WchB;
    int cj = j_lo + c;

    __shared__ __align__(16) unsigned char smem[SMEMG2];
    const int t = threadIdx.x;
    const int lane = t & 63, wvi = t >> 6, l16 = lane & 15, quad = lane >> 4;

    unsigned short* HbC = HbB + (size_t)(d & 1) * (H_ * 32 * D_);
    float* CbC = Cbf + (size_t)(d & 1) * (H_ * 32 * D_);

    f32x4 acc[2][2] = {};
    const int arow = t >> 3, acol = (t & 7) * 8;
    const int brow = t >> 1, bcol = (t & 1) * 32;
    const unsigned short* asrc = Ain + (size_t)(c * 32 + arow) * TWOD + acol;
    const unsigned short* wsrc = W + (size_t)(ntile * 128 + brow) * TWOD + bcol;

    uint4 aR, bR0, bR1, bR2, bR3;
    #define LOAD_STEP(s_)                                                      \
        {                                                                      \
            aR = *(const uint4*)(asrc + (s_) * 64);                            \
            const uint4* s4 = (const uint4*)(wsrc + (s_) * 64);                \
            bR0 = s4[0]; bR1 = s4[1]; bR2 = s4[2]; bR3 = s4[3];                \
        }
    #define STORE_STEP(p_)                                                     \
        {                                                                      \
            unsigned short (*At_)[72] = (unsigned short (*)[72])(smem + (p_) * BUFSZ); \
            unsigned short (*Bt_)[72] = (unsigned short (*)[72])(smem + (p_) * BUFSZ + 4608); \
            *(uint4*)&At_[arow][acol] = aR;                                    \
            uint4* dp = (uint4*)&Bt_[brow][bcol];                              \
            dp[0] = bR0; dp[1] = bR1; dp[2] = bR2; dp[3] = bR3;                \
        }

    LOAD_STEP(0);
    STORE_STEP(0);
    __syncthreads();
    for (int s = 0; s < 16; ++s) {
        if (s < 15) LOAD_STEP(s + 1);
        int p = s & 1;
        unsigned short (*At)[72] = (unsigned short (*)[72])(smem + p * BUFSZ);
        unsigned short (*Bt)[72] = (unsigned short (*)[72])(smem + p * BUFSZ + 4608);
        for (int ks = 0; ks < 2; ++ks) {
            bf16x8 a0 = *(const bf16x8*)&At[l16][ks * 32 + quad * 8];
            bf16x8 a1 = *(const bf16x8*)&At[16 + l16][ks * 32 + quad * 8];
            bf16x8 b0 = *(const bf16x8*)&Bt[wvi * 32 + l16][ks * 32 + quad * 8];
            bf16x8 b1 = *(const bf16x8*)&Bt[wvi * 32 + 16 + l16][ks * 32 + quad * 8];
            acc[0][0] = __builtin_amdgcn_mfma_f32_16x16x32_bf16(a0, b0, acc[0][0], 0, 0, 0);
            acc[0][1] = __builtin_amdgcn_mfma_f32_16x16x32_bf16(a0, b1, acc[0][1], 0, 0, 0);
            acc[1][0] = __builtin_amdgcn_mfma_f32_16x16x32_bf16(a1, b0, acc[1][0], 0, 0, 0);
            acc[1][1] = __builtin_amdgcn_mfma_f32_16x16x32_bf16(a1, b1, acc[1][1], 0, 0, 0);
        }
        if (s < 15) {
            STORE_STEP(1 - p);
            __syncthreads();
        }
    }
    #undef LOAD_STEP
    #undef STORE_STEP

    for (int mi = 0; mi < 2; ++mi) {
        int rr = mi * 16 + quad * 4;
        for (int ni = 0; ni < 2; ++ni) {
            int n = ntile * 128 + wvi * 32 + ni * 16 + l16;
            float bsv = z ? bcc[n] : bch[n];
            for (int r = 0; r < 4; ++r) {
                int rb = rr + r;
                float val = acc[mi][ni][r] + bsv;
                if (z) {
                    CbC[(size_t)(cj * 32 + rb) * D_ + n] = val;
                } else {
                    HbC[(size_t)(cj * 32 + rb) * D_ + n] = f2bf(val);
                    if (d == P_ + H_ - 2)
                        Hf[(size_t)(cj * 32 + rb) * D_ + n] = val;
                }
            }
        }
    }
}

// ============ MLP head =====================================================
__global__ __launch_bounds__(256) void k_fc(
        const float* __restrict__ hin, const float* __restrict__ W,
        const float* __restrict__ bias, float* __restrict__ outv) {
    int g = blockIdx.x * 256 + threadIdx.x;   // 16384 total
    int col = g & 511, rb = g >> 9;
    const float* h = hin + (size_t)rb * D_;
    const float* w = W + (size_t)col * D_;
    float accv = bias[col];
    for (int k = 0; k < D_; k += 4) {
        float4 wv4 = *(const float4*)(w + k);
        float4 hv = *(const float4*)(h + k);
        accv += hv.x * wv4.x + hv.y * wv4.y + hv.z * wv4.z + hv.w * wv4.w;
    }
    outv[(size_t)rb * D_ + col] = fmaxf(accv, 0.0f);
}

__global__ __launch_bounds__(128) void k_sm(
        const float* __restrict__ T2, const float* __restrict__ W3,
        const float* __restrict__ b3, float* __restrict__ out) {
    __shared__ float lg[96];
    int t = threadIdx.x;
    if (t < 96) {
        int rb = t / 3, cls = t % 3;
        const float* h = T2 + (size_t)rb * D_;
        const float* w = W3 + (size_t)cls * D_;
        float accv = b3[cls];
        for (int k = 0; k < D_; k += 4) {
            float4 wv4 = *(const float4*)(w + k);
            float4 hv = *(const float4*)(h + k);
            accv += hv.x * wv4.x + hv.y * wv4.y + hv.z * wv4.z + hv.w * wv4.w;
        }
        lg[rb * 3 + cls] = accv;
    }
    __syncthreads();
    if (t < 32) {
        float a = lg[t * 3 + 0], bq = lg[t * 3 + 1], cq = lg[t * 3 + 2];
        float m = fmaxf(a, fmaxf(bq, cq));
        float ea = __expf(a - m), eb = __expf(bq - m), ec = __expf(cq - m);
        float s = 1.0f / (ea + eb + ec);
        out[t * 3 + 0] = ea * s;
        out[t * 3 + 1] = eb * s;
        out[t * 3 + 2] = ec * s;
    }
}

// ---------------------------------------------------------------------------
extern "C" void kernel_launch(void* const* d_in, const int* in_sizes, int n_in,
                              void* d_out, int out_size, void* d_ws, size_t ws_size,
                              hipStream_t stream) {
    (void)in_sizes; (void)n_in; (void)out_size; (void)ws_size;

    const int* prem = (const int*)d_in[0];
    const int* hyp  = (const int*)d_in[1];
    const float* emb = (const float*)d_in[2];
    const float* Wih = (const float*)d_in[3];
    const float* Whh = (const float*)d_in[4];
    const float* bih = (const float*)d_in[5];
    const float* bhh = (const float*)d_in[6];
    const float* Wch = (const float*)d_in[7];
    const float* bch = (const float*)d_in[8];
    const float* Wcc = (const float*)d_in[9];
    const float* bcc = (const float*)d_in[10];
    const float* W1  = (const float*)d_in[11];
    const float* b1  = (const float*)d_in[12];
    const float* W2  = (const float*)d_in[13];
    const float* b2  = (const float*)d_in[14];
    const float* W3  = (const float*)d_in[15];
    const float* b3  = (const float*)d_in[16];
    float* outp = (float*)d_out;
    char* wsb = (char*)d_ws;

    float* Hf = (float*)(wsb + OFF_HF);
    float* T1 = (float*)(wsb + OFF_T1);
    float* T2 = (float*)(wsb + OFF_T2);

    k_p0<<<512, 256, 0, stream>>>(prem, hyp, emb, Whh, Wch, Wcc, wsb);
    k_p1<<<768, 256, 0, stream>>>(Wih, bih, bhh, wsb);
    for (int d = 0; d < P_ + H_ - 1; ++d) {
        int j_lo = (d > P_ - 1) ? d - (P_ - 1) : 0;
        int j_hi = (d < H_ - 1) ? d : H_ - 1;
        int ncells = j_hi - j_lo + 1;
        k_gates<<<ncells * 32, 256, 0, stream>>>(d, ncells, wsb);
        k_cond<<<ncells * 8, 256, 0, stream>>>(d, bch, bcc, wsb);
    }
    const float* hfin = Hf + (size_t)(H_ - 1) * 32 * D_;
    k_fc<<<64, 256, 0, stream>>>(hfin, W1, b1, T1);
    k_fc<<<64, 256, 0, stream>>>(T1, W2, b2, T2);
    k_sm<<<1, 128, 0, stream>>>(T2, W3, b3, outp);
}